// Round 6
// baseline (1979.722 us; speedup 1.0000x reference)
//
#include <hip/hip_runtime.h>
#include <math.h>

#define TT 512
#define BB 128
#define KK 9

// ---------------------------------------------------------------------------
// fast activations: v_exp_f32 / v_rcp_f32 based (~1 ulp each)
// ---------------------------------------------------------------------------
__device__ __forceinline__ float fast_sigmoid(float x) {
    const float LOG2E = 1.4426950408889634f;
    float e = __builtin_amdgcn_exp2f(-x * LOG2E);
    return __builtin_amdgcn_rcpf(1.0f + e);
}
__device__ __forceinline__ float fast_tanh(float x) {
    const float LOG2E = 1.4426950408889634f;
    float a = fabsf(x);
    float e = __builtin_amdgcn_exp2f(-2.0f * a * LOG2E);   // in (0,1]
    float t = (1.0f - e) * __builtin_amdgcn_rcpf(1.0f + e);
    return copysignf(t, x);
}

// ---------------------------------------------------------------------------
// E: dense embedding gather. e[(t*128+b)*128 + d] = emb[x[b][t]*128 + d]
// ---------------------------------------------------------------------------
__global__ __launch_bounds__(256) void gather_e(
    const int* __restrict__ x, const float* __restrict__ emb,
    float* __restrict__ e)
{
    const int row  = blockIdx.x * 8 + (threadIdx.x >> 5);   // t*128+b
    const int lane = threadIdx.x & 31;
    const int t = row >> 7;
    const int b = row & 127;
    const int tok = x[b * TT + t];
    const float4 v = *(const float4*)(emb + (size_t)tok * 128 + lane * 4);
    *(float4*)(e + (size_t)row * 128 + lane * 4) = v;
}

// ---------------------------------------------------------------------------
// G: input projection for one time-chunk, both directions (grid.z = dir).
// Software-pipelined: chunk k+1's global loads issue BEFORE chunk k's
// compute, hiding L2 latency (R5: loads were issued after prev compute ->
// latency exposed every one of 16 iterations).
// Epilogue stores into the LSTM's THREAD-ORDER permuted layout:
//   gate row r = q*128+k  ->  column j = (k>>4)*64 + (k&15)*4 + q
// so lstm's per-step xw read is one coalesced b32 per wave.
// ---------------------------------------------------------------------------
__global__ __launch_bounds__(256) void input_gemm(
    const float* __restrict__ e,
    const float* __restrict__ w_ih_f, const float* __restrict__ w_ih_b,
    const float* __restrict__ b_ih_f, const float* __restrict__ b_hh_f,
    const float* __restrict__ b_ih_b, const float* __restrict__ b_hh_b,
    float* __restrict__ buf_f, float* __restrict__ buf_b,
    int t0f, int t0b)
{
    const int dir = blockIdx.z;
    const int s   = blockIdx.x;           // local timestep within chunk
    const int n0  = blockIdx.y * 128;     // gate tile base; qgate = n0>>7
    const int t   = (dir ? t0b : t0f) + s;
    const float* w  = dir ? w_ih_b : w_ih_f;
    const float* bi = dir ? b_ih_b : b_ih_f;
    const float* bh = dir ? b_hh_b : b_hh_f;
    float* dst = dir ? buf_b : buf_f;

    __shared__ __align__(16) float As[8][132];
    __shared__ __align__(16) float Bs[8][4][36];

    const int tid = threadIdx.x;
    const int tx = tid & 15;
    const int ty = tid >> 4;
    const int li = tid & 127;
    const int kb = (tid >> 7) * 4;   // 0 or 4

    const float* wrow = w + (size_t)(n0 + li) * 128;
    const float* arow = e + ((size_t)t * 128 + li) * 128;

    float acc[8][8];
    #pragma unroll
    for (int i = 0; i < 8; i++)
        #pragma unroll
        for (int j = 0; j < 8; j++) acc[i][j] = 0.0f;

    const int bsub = li >> 5, boff = li & 31;

    // preload chunk 0
    float4 a_reg = *(const float4*)(arow + kb);
    float4 b_reg = *(const float4*)(wrow + kb);

    for (int kc = 0; kc < 128; kc += 8) {
        __syncthreads();
        As[kb + 0][li] = a_reg.x; As[kb + 1][li] = a_reg.y;
        As[kb + 2][li] = a_reg.z; As[kb + 3][li] = a_reg.w;
        Bs[kb + 0][bsub][boff] = b_reg.x; Bs[kb + 1][bsub][boff] = b_reg.y;
        Bs[kb + 2][bsub][boff] = b_reg.z; Bs[kb + 3][bsub][boff] = b_reg.w;
        __syncthreads();
        if (kc + 8 < 128) {
            a_reg = *(const float4*)(arow + kc + 8 + kb);
            b_reg = *(const float4*)(wrow + kc + 8 + kb);
        }
        #pragma unroll
        for (int kk = 0; kk < 8; kk++) {
            float4 af0 = *(const float4*)&As[kk][ty * 8];
            float4 af1 = *(const float4*)&As[kk][ty * 8 + 4];
            float4 bf0 = *(const float4*)&Bs[kk][tx >> 2][(tx & 3) * 8];
            float4 bf1 = *(const float4*)&Bs[kk][tx >> 2][(tx & 3) * 8 + 4];
            float a_[8] = {af0.x, af0.y, af0.z, af0.w, af1.x, af1.y, af1.z, af1.w};
            float b_[8] = {bf0.x, bf0.y, bf0.z, bf0.w, bf1.x, bf1.y, bf1.z, bf1.w};
            #pragma unroll
            for (int i = 0; i < 8; i++)
                #pragma unroll
                for (int j = 0; j < 8; j++)
                    acc[i][j] += a_[i] * b_[j];
        }
    }

    // epilogue: add bias, store permuted (thread-order) columns
    const int qgate = n0 >> 7;           // gate type of this tile
    const int nbase = n0 + tx * 8;
    float bias[8];
    #pragma unroll
    for (int j = 0; j < 8; j++) {
        int n = nbase + j;
        bias[j] = bi[n] + bh[n];
    }
    const int w_  = tx >> 1;
    const int mb  = (tx & 1) * 8;
    #pragma unroll
    for (int i = 0; i < 8; i++) {
        int brow = ty * 8 + i;
        float* o = dst + ((size_t)s * 128 + brow) * 512;
        #pragma unroll
        for (int jj = 0; jj < 8; jj++) {
            int jcol = w_ * 64 + (mb + jj) * 4 + qgate;
            o[jcol] = acc[i][jj] + bias[jj];
        }
    }
}

// ---------------------------------------------------------------------------
// L: LSTM recurrence, one block (512 thr, 8 waves) per (dir, batch-row).
// Gate-group layout: lanes {4m..4m+3} of wave w hold gates {i,f,g,o} of
// h-index k = w*16+m. 128 weights/thread (fully-unrolled dot keeps them in
// VGPRs; partial unroll demotes to scratch -- R3 lesson). Gate exchange =
// 3 in-wave shfl_xor. ONE barrier per step. Emissions are NOT folded
// (R5: the 10 LDS-pipe ops + serial reduce tail sat on the lockstep
// critical path every step); instead q==0 lanes write h to global h_all.
// xw read is coalesced b32 (buf stored in thread order by input_gemm).
// ---------------------------------------------------------------------------
__global__ __launch_bounds__(512, 2) void lstm_chunk(
    const float* __restrict__ buf_f, const float* __restrict__ buf_b,
    const float* __restrict__ w_hh_f, const float* __restrict__ w_hh_b,
    float* __restrict__ h_all,
    float* __restrict__ h_state, float* __restrict__ c_state,
    int t0f, int t0b, int C, int init)
{
    const int dir = blockIdx.x >> 7;
    const int b   = blockIdx.x & 127;
    const int j   = threadIdx.x;
    const int w_  = j >> 6;          // wave id 0..7
    const int l   = j & 63;
    const int m   = l >> 2;          // group 0..15
    const int q   = l & 3;           // gate: 0=i 1=f 2=g 3=o
    const int k   = w_ * 16 + m;     // h index 0..127
    const int r   = q * 128 + k;     // gate row in [0,512)

    const float* whh = dir ? w_hh_b : w_hh_f;
    float wR[128];
    #pragma unroll
    for (int qq = 0; qq < 32; qq++) {
        float4 v = *(const float4*)(whh + (size_t)r * 128 + qq * 4);
        wR[4*qq+0] = v.x; wR[4*qq+1] = v.y; wR[4*qq+2] = v.z; wR[4*qq+3] = v.w;
    }

    __shared__ __align__(16) float h_lds[2][128];
    float c;
    if (init) {
        c = 0.0f;
        if (q == 0) h_lds[0][k] = 0.0f;
    } else {
        c = c_state[((size_t)dir * 128 + b) * 128 + k];
        if (q == 0) h_lds[0][k] = h_state[((size_t)dir * 128 + b) * 128 + k];
    }
    __syncthreads();

    const float* buf = dir ? buf_b : buf_f;
    const int t0     = dir ? t0b : t0f;
    const int  tl0   = dir ? (C - 1) : 0;
    const long lstep = dir ? -(long)(128 * 512) : (long)(128 * 512);

    const float* xp = buf + ((size_t)tl0 * 128 + b) * 512 + j;
    float xw = *xp;
    float h_reg = 0.0f;

    for (int s = 0; s < C; s++) {
        const int t = t0 + (dir ? (C - 1 - s) : s);
        const int p = s & 1;
        const float* hprev = h_lds[p];

        float a0 = 0.f, a1 = 0.f, a2 = 0.f, a3 = 0.f;
        #pragma unroll
        for (int qq = 0; qq < 32; qq++) {
            float4 h4 = *(const float4*)&hprev[4 * qq];
            a0 += wR[4*qq+0] * h4.x;
            a1 += wR[4*qq+1] * h4.y;
            a2 += wR[4*qq+2] * h4.z;
            a3 += wR[4*qq+3] * h4.w;
        }
        float pre = xw + ((a0 + a1) + (a2 + a3));

        // prefetch next xw early (covered by activation/exchange tail)
        if (s + 1 < C) { xp += lstep; xw = *xp; }

        float act = (q == 2) ? fast_tanh(pre) : fast_sigmoid(pre);

        // in-group exchange (valid combination only on q==0 lanes):
        float f_ = __shfl_xor(act, 1);   // q0 <- q1 (f)
        float g_ = __shfl_xor(act, 2);   // q0 <- q2 (g)
        float o_ = __shfl_xor(f_, 2);    // q0 <- q3 (o)

        c = f_ * c + act * g_;           // act == i on q0
        h_reg = o_ * fast_tanh(c);
        if (q == 0) {
            h_lds[p ^ 1][k] = h_reg;
            h_all[((size_t)t * BB + b) * 256 + dir * 128 + k] = h_reg;
        }

        __syncthreads();                 // h_t visible to all waves
    }

    if (q == 0) {
        h_state[((size_t)dir * 128 + b) * 128 + k] = h_reg;
        c_state[((size_t)dir * 128 + b) * 128 + k] = c;
    }
}

// ---------------------------------------------------------------------------
// M: emissions = h_all @ W_tag^T + b_tag. One wave per (t,b) row.
// Memory-bound: 64 MB h read.
// ---------------------------------------------------------------------------
__global__ __launch_bounds__(256) void emis_kernel(
    const float* __restrict__ h_all, const float* __restrict__ W_tag,
    const float* __restrict__ b_tag, float* __restrict__ em_sum)
{
    const int wid  = threadIdx.x >> 6;
    const int lane = threadIdx.x & 63;
    const size_t m = (size_t)blockIdx.x * 4 + wid;   // row = t*B + b
    const float4 hv = *(const float4*)(h_all + m * 256 + lane * 4);
    #pragma unroll
    for (int kk = 0; kk < KK; kk++) {
        const float4 wv = *(const float4*)(W_tag + kk * 256 + lane * 4);
        float p = hv.x * wv.x + hv.y * wv.y + hv.z * wv.z + hv.w * wv.w;
        #pragma unroll
        for (int off = 32; off > 0; off >>= 1) p += __shfl_down(p, off);
        if (lane == 0) em_sum[m * KK + kk] = p + b_tag[kk];
    }
}

// ---------------------------------------------------------------------------
// V: Viterbi decode. One block (64 threads) per batch row; emissions and
// backpointers LDS-resident. 9 shfls hoisted (independent) before the
// max chain. First-max tie-break (ascending, strict >).
// ---------------------------------------------------------------------------
__global__ __launch_bounds__(64) void viterbi_kernel(
    const float* __restrict__ em_sum,
    const float* __restrict__ start_trans, const float* __restrict__ end_trans,
    const float* __restrict__ trans, int* __restrict__ out)
{
    const int b = blockIdx.x;
    const int lane = threadIdx.x;
    __shared__ float em_s[TT * KK];
    __shared__ unsigned char bp[TT][KK];

    for (int f = lane; f < TT * KK; f += 64) {
        int t = f / KK, kk = f - t * KK;
        em_s[f] = em_sum[((size_t)t * BB + b) * KK + kk];
    }
    __syncthreads();

    float trans_col[KK];
    float score = -1e30f;
    if (lane < KK) {
        #pragma unroll
        for (int i = 0; i < KK; i++) trans_col[i] = trans[i * KK + lane];
        score = start_trans[lane] + em_s[lane];
    }

    for (int t = 1; t < TT; t++) {
        float my = (lane < KK) ? score : -1e30f;
        float sarr[KK];
        #pragma unroll
        for (int i = 0; i < KK; i++) sarr[i] = __shfl(my, i);
        float best = -1e30f;
        int bi = 0;
        #pragma unroll
        for (int i = 0; i < KK; i++) {
            float cand = sarr[i] + trans_col[i];
            if (cand > best) { best = cand; bi = i; }
        }
        if (lane < KK) {
            bp[t][lane] = (unsigned char)bi;
            score = best + em_s[t * KK + lane];
        }
    }

    float fin = (lane < KK) ? (score + end_trans[lane]) : -1e30f;
    float farr[KK];
    #pragma unroll
    for (int jx = 0; jx < KK; jx++) farr[jx] = __shfl(fin, jx);
    float bestf = -1e30f;
    int bj = 0;
    #pragma unroll
    for (int jx = 0; jx < KK; jx++) {
        if (farr[jx] > bestf) { bestf = farr[jx]; bj = jx; }
    }

    if (lane == 0) {
        int tag = bj;
        out[b * TT + (TT - 1)] = tag;
        for (int t = TT - 1; t >= 1; t--) {
            tag = bp[t][tag];
            out[b * TT + t - 1] = tag;
        }
    }
}

// ---------------------------------------------------------------------------
extern "C" void kernel_launch(void* const* d_in, const int* in_sizes, int n_in,
                              void* d_out, int out_size, void* d_ws, size_t ws_size,
                              hipStream_t stream)
{
    const int*   x       = (const int*)  d_in[0];
    const float* emb     = (const float*)d_in[1];
    const float* w_ih_f  = (const float*)d_in[2];
    const float* w_hh_f  = (const float*)d_in[3];
    const float* b_ih_f  = (const float*)d_in[4];
    const float* b_hh_f  = (const float*)d_in[5];
    const float* w_ih_b  = (const float*)d_in[6];
    const float* w_hh_b  = (const float*)d_in[7];
    const float* b_ih_b  = (const float*)d_in[8];
    const float* b_hh_b  = (const float*)d_in[9];
    const float* W_tag   = (const float*)d_in[10];
    const float* b_tag   = (const float*)d_in[11];
    const float* start_t = (const float*)d_in[12];
    const float* end_t   = (const float*)d_in[13];
    const float* trans   = (const float*)d_in[14];
    int* out = (int*)d_out;

    // fixed-size pieces (floats)
    const size_t e_elems     = (size_t)TT * BB * 128;  // 33.5 MB
    const size_t hall_elems  = (size_t)TT * BB * 256;  // 67 MB
    const size_t em_elems    = (size_t)TT * BB * KK;   // 2.25 MB
    const size_t state_elems = (size_t)2 * 128 * 128;

    // pick chunk size C based on available workspace
    int C = 32;
    const int cands[5] = {512, 256, 128, 64, 32};
    for (int ci = 0; ci < 5; ci++) {
        size_t need = ((size_t)2 * cands[ci] * BB * 512
                       + e_elems + hall_elems + em_elems
                       + 2 * state_elems) * sizeof(float);
        if (ws_size >= need) { C = cands[ci]; break; }
    }

    float* buf_f   = (float*)d_ws;                       // C*128*512
    float* buf_b   = buf_f + (size_t)C * BB * 512;       // C*128*512
    float* em_sum  = buf_b + (size_t)C * BB * 512;       // T*B*9
    float* h_state = em_sum + em_elems;                  // 2*128*128
    float* c_state = h_state + state_elems;              // 2*128*128
    float* e       = c_state + state_elems;              // T*B*128
    float* h_all   = e + e_elems;                        // T*B*256

    gather_e<<<dim3((TT * BB) / 8), dim3(256), 0, stream>>>(x, emb, e);

    const int rounds = TT / C;
    for (int r = 0; r < rounds; r++) {
        const int t0f = r * C;
        const int t0b = TT - (r + 1) * C;
        dim3 gg(C, 4, 2);
        input_gemm<<<gg, dim3(256), 0, stream>>>(
            e, w_ih_f, w_ih_b, b_ih_f, b_hh_f, b_ih_b, b_hh_b,
            buf_f, buf_b, t0f, t0b);
        lstm_chunk<<<dim3(256), dim3(512), 0, stream>>>(
            buf_f, buf_b, w_hh_f, w_hh_b, h_all,
            h_state, c_state, t0f, t0b, C, (r == 0) ? 1 : 0);
    }
    emis_kernel<<<dim3((TT * BB) / 4), dim3(256), 0, stream>>>(
        h_all, W_tag, b_tag, em_sum);
    viterbi_kernel<<<dim3(BB), dim3(64), 0, stream>>>(
        em_sum, start_t, end_t, trans, out);
}

// Round 7
// 1026.658 us; speedup vs baseline: 1.9283x; 1.9283x over previous
//
#include <hip/hip_runtime.h>
#include <math.h>

#define TT 512
#define BB 128
#define KK 9

// ---------------------------------------------------------------------------
// fast activations: v_exp_f32 / v_rcp_f32 based (~1 ulp each)
// ---------------------------------------------------------------------------
__device__ __forceinline__ float fast_sigmoid(float x) {
    const float LOG2E = 1.4426950408889634f;
    float e = __builtin_amdgcn_exp2f(-x * LOG2E);
    return __builtin_amdgcn_rcpf(1.0f + e);
}
__device__ __forceinline__ float fast_tanh(float x) {
    const float LOG2E = 1.4426950408889634f;
    float a = fabsf(x);
    float e = __builtin_amdgcn_exp2f(-2.0f * a * LOG2E);   // in (0,1]
    float t = (1.0f - e) * __builtin_amdgcn_rcpf(1.0f + e);
    return copysignf(t, x);
}

// ---------------------------------------------------------------------------
// E: dense embedding gather. e[(t*128+b)*128 + d] = emb[x[b][t]*128 + d]
// ---------------------------------------------------------------------------
__global__ __launch_bounds__(256) void gather_e(
    const int* __restrict__ x, const float* __restrict__ emb,
    float* __restrict__ e)
{
    const int row  = blockIdx.x * 8 + (threadIdx.x >> 5);   // t*128+b
    const int lane = threadIdx.x & 31;
    const int t = row >> 7;
    const int b = row & 127;
    const int tok = x[b * TT + t];
    const float4 v = *(const float4*)(emb + (size_t)tok * 128 + lane * 4);
    *(float4*)(e + (size_t)row * 128 + lane * 4) = v;
}

// ---------------------------------------------------------------------------
// G: input projection, whole-K in LDS, ONE barrier per block.
// Block = one (timestep, 128-gate tile, dir): A(128 rows x 128 k) and
// B(128 gates x 128 k) staged entirely (141 KB LDS), then 8192 FMA/thread
// with no further syncs. R5's chunked version had 32 barriers/block and
// exposed L2 latency between chunks (~6x over the 109 us VALU floor).
// Stores: float4, standard layout (R6 scatter epilogue destroyed
// write coalescing -- reverted).
// ---------------------------------------------------------------------------
__global__ __launch_bounds__(256, 1) void input_gemm(
    const float* __restrict__ e,
    const float* __restrict__ w_ih_f, const float* __restrict__ w_ih_b,
    const float* __restrict__ b_ih_f, const float* __restrict__ b_hh_f,
    const float* __restrict__ b_ih_b, const float* __restrict__ b_hh_b,
    float* __restrict__ buf_f, float* __restrict__ buf_b,
    int t0f, int t0b)
{
    const int dir = blockIdx.z;
    const int s   = blockIdx.x;           // local timestep within chunk
    const int n0  = blockIdx.y * 128;     // gate tile base
    const int t   = (dir ? t0b : t0f) + s;
    const float* w  = dir ? w_ih_b : w_ih_f;
    const float* bi = dir ? b_ih_b : b_ih_f;
    const float* bh = dir ? b_hh_b : b_hh_f;
    float* dst = dir ? buf_b : buf_f;

    __shared__ __align__(16) float As[128][132];     // [k][row]  67.6 KB
    __shared__ __align__(16) float Bs[128][4][36];   // [k][sub][off] 73.7 KB

    const int tid = threadIdx.x;
    const int tx = tid & 15;
    const int ty = tid >> 4;
    const int li = tid & 127;            // row / gate index within tile
    const int kb = (tid >> 7) * 4;       // 0 or 4

    const float* arow = e + ((size_t)t * 128 + li) * 128;
    const float* wrow = w + (size_t)(n0 + li) * 128;

    // stage ALL of A and B: 16+16 float4 loads issued back-to-back
    float4 aR[16], bR[16];
    #pragma unroll
    for (int r = 0; r < 16; r++) aR[r] = *(const float4*)(arow + r * 8 + kb);
    #pragma unroll
    for (int r = 0; r < 16; r++) bR[r] = *(const float4*)(wrow + r * 8 + kb);

    const int bsub = li >> 5, boff = li & 31;
    #pragma unroll
    for (int r = 0; r < 16; r++) {
        As[r * 8 + kb + 0][li] = aR[r].x;
        As[r * 8 + kb + 1][li] = aR[r].y;
        As[r * 8 + kb + 2][li] = aR[r].z;
        As[r * 8 + kb + 3][li] = aR[r].w;
        Bs[r * 8 + kb + 0][bsub][boff] = bR[r].x;
        Bs[r * 8 + kb + 1][bsub][boff] = bR[r].y;
        Bs[r * 8 + kb + 2][bsub][boff] = bR[r].z;
        Bs[r * 8 + kb + 3][bsub][boff] = bR[r].w;
    }
    __syncthreads();                     // the only barrier

    float acc[8][8];
    #pragma unroll
    for (int i = 0; i < 8; i++)
        #pragma unroll
        for (int j = 0; j < 8; j++) acc[i][j] = 0.0f;

    #pragma unroll 8
    for (int k = 0; k < 128; k++) {
        float4 af0 = *(const float4*)&As[k][ty * 8];
        float4 af1 = *(const float4*)&As[k][ty * 8 + 4];
        float4 bf0 = *(const float4*)&Bs[k][tx >> 2][(tx & 3) * 8];
        float4 bf1 = *(const float4*)&Bs[k][tx >> 2][(tx & 3) * 8 + 4];
        float a_[8] = {af0.x, af0.y, af0.z, af0.w, af1.x, af1.y, af1.z, af1.w};
        float b_[8] = {bf0.x, bf0.y, bf0.z, bf0.w, bf1.x, bf1.y, bf1.z, bf1.w};
        #pragma unroll
        for (int i = 0; i < 8; i++)
            #pragma unroll
            for (int j = 0; j < 8; j++)
                acc[i][j] += a_[i] * b_[j];
    }

    // epilogue: add bias, float4 stores, standard layout
    const int nbase = n0 + tx * 8;
    float bias[8];
    #pragma unroll
    for (int j = 0; j < 8; j++) {
        int n = nbase + j;
        bias[j] = bi[n] + bh[n];
    }
    #pragma unroll
    for (int i = 0; i < 8; i++) {
        int brow = ty * 8 + i;
        float* o = dst + ((size_t)s * 128 + brow) * 512 + nbase;
        float4 v0, v1;
        v0.x = acc[i][0] + bias[0]; v0.y = acc[i][1] + bias[1];
        v0.z = acc[i][2] + bias[2]; v0.w = acc[i][3] + bias[3];
        v1.x = acc[i][4] + bias[4]; v1.y = acc[i][5] + bias[5];
        v1.z = acc[i][6] + bias[6]; v1.w = acc[i][7] + bias[7];
        *(float4*)o = v0;
        *(float4*)(o + 4) = v1;
    }
}

// ---------------------------------------------------------------------------
// L: LSTM recurrence, one block (512 thr, 8 waves) per (dir, batch-row).
// Gate-group layout: lanes {4m..4m+3} of wave w hold gates {i,f,g,o} of
// h-index k = w*16+m. 128 weights/thread, dot fully unrolled (partial
// unroll demotes to scratch -- R3). ONE barrier per step; ALL global ops
// (xw prefetch, h_all store) issued immediately POST-barrier so the
// pre-barrier vmcnt(0) drain has a full step of slack (R6 lesson: issuing
// them pre-barrier puts store latency on the critical path every step).
// Gate exchange: 3 INDEPENDENT shfl_xor (xor 1,2,3).
// ---------------------------------------------------------------------------
__global__ __launch_bounds__(512, 2) void lstm_chunk(
    const float* __restrict__ buf_f, const float* __restrict__ buf_b,
    const float* __restrict__ w_hh_f, const float* __restrict__ w_hh_b,
    float* __restrict__ h_all,
    float* __restrict__ h_state, float* __restrict__ c_state,
    int t0f, int t0b, int C, int init)
{
    const int dir = blockIdx.x >> 7;
    const int b   = blockIdx.x & 127;
    const int j   = threadIdx.x;
    const int w_  = j >> 6;          // wave id 0..7
    const int l   = j & 63;
    const int m   = l >> 2;          // group 0..15
    const int q   = l & 3;           // gate: 0=i 1=f 2=g 3=o
    const int k   = w_ * 16 + m;     // h index 0..127
    const int r   = q * 128 + k;     // gate row in [0,512)

    const float* whh = dir ? w_hh_b : w_hh_f;
    float wR[128];
    #pragma unroll
    for (int qq = 0; qq < 32; qq++) {
        float4 v = *(const float4*)(whh + (size_t)r * 128 + qq * 4);
        wR[4*qq+0] = v.x; wR[4*qq+1] = v.y; wR[4*qq+2] = v.z; wR[4*qq+3] = v.w;
    }

    __shared__ __align__(16) float h_lds[2][128];
    float c;
    if (init) {
        c = 0.0f;
        if (q == 0) h_lds[0][k] = 0.0f;
    } else {
        c = c_state[((size_t)dir * 128 + b) * 128 + k];
        if (q == 0) h_lds[0][k] = h_state[((size_t)dir * 128 + b) * 128 + k];
    }
    __syncthreads();

    const float* buf = dir ? buf_b : buf_f;
    const int t0     = dir ? t0b : t0f;
    const int  tl0   = dir ? (C - 1) : 0;
    const long lstep = dir ? -(long)(128 * 512) : (long)(128 * 512);

    const float* xp = buf + ((size_t)tl0 * 128 + b) * 512 + r;
    float xw = *xp;
    float h_reg = 0.0f;
    int   t_prev = 0;
    bool  have_store = false;

    for (int s = 0; s < C; s++) {
        const int t = t0 + (dir ? (C - 1 - s) : s);
        const int p = s & 1;
        const float* hprev = h_lds[p];

        float a0 = 0.f, a1 = 0.f, a2 = 0.f, a3 = 0.f;
        #pragma unroll
        for (int qq = 0; qq < 32; qq++) {
            float4 h4 = *(const float4*)&hprev[4 * qq];
            a0 += wR[4*qq+0] * h4.x;
            a1 += wR[4*qq+1] * h4.y;
            a2 += wR[4*qq+2] * h4.z;
            a3 += wR[4*qq+3] * h4.w;
        }
        float pre = xw + ((a0 + a1) + (a2 + a3));

        float act = (q == 2) ? fast_tanh(pre) : fast_sigmoid(pre);

        // independent in-group exchanges (q0 lane gets valid i,f,g,o):
        float f_ = __shfl_xor(act, 1);   // q0 <- q1 (f)
        float g_ = __shfl_xor(act, 2);   // q0 <- q2 (g)
        float o_ = __shfl_xor(act, 3);   // q0 <- q3 (o)

        c = f_ * c + act * g_;           // act == i on q0
        h_reg = o_ * fast_tanh(c);
        if (q == 0) h_lds[p ^ 1][k] = h_reg;

        __syncthreads();                 // h_t visible to all waves

        // post-barrier: issue global ops with a full step of slack
        if (s + 1 < C) { xp += lstep; xw = *xp; }
        if (q == 0)
            h_all[((size_t)t * BB + b) * 256 + dir * 128 + k] = h_reg;
        t_prev = t; have_store = true;
        (void)t_prev; (void)have_store;
    }

    if (q == 0) {
        h_state[((size_t)dir * 128 + b) * 128 + k] = h_reg;
        c_state[((size_t)dir * 128 + b) * 128 + k] = c;
    }
}

// ---------------------------------------------------------------------------
// M: emissions = h_all @ W_tag^T + b_tag. One wave per (t,b) row.
// ---------------------------------------------------------------------------
__global__ __launch_bounds__(256) void emis_kernel(
    const float* __restrict__ h_all, const float* __restrict__ W_tag,
    const float* __restrict__ b_tag, float* __restrict__ em_sum)
{
    const int wid  = threadIdx.x >> 6;
    const int lane = threadIdx.x & 63;
    const size_t m = (size_t)blockIdx.x * 4 + wid;   // row = t*B + b
    const float4 hv = *(const float4*)(h_all + m * 256 + lane * 4);
    #pragma unroll
    for (int kk = 0; kk < KK; kk++) {
        const float4 wv = *(const float4*)(W_tag + kk * 256 + lane * 4);
        float p = hv.x * wv.x + hv.y * wv.y + hv.z * wv.z + hv.w * wv.w;
        #pragma unroll
        for (int off = 32; off > 0; off >>= 1) p += __shfl_down(p, off);
        if (lane == 0) em_sum[m * KK + kk] = p + b_tag[kk];
    }
}

// ---------------------------------------------------------------------------
// V: Viterbi decode. One block (64 threads) per batch row; emissions and
// backpointers LDS-resident. First-max tie-break (ascending, strict >).
// ---------------------------------------------------------------------------
__global__ __launch_bounds__(64) void viterbi_kernel(
    const float* __restrict__ em_sum,
    const float* __restrict__ start_trans, const float* __restrict__ end_trans,
    const float* __restrict__ trans, int* __restrict__ out)
{
    const int b = blockIdx.x;
    const int lane = threadIdx.x;
    __shared__ float em_s[TT * KK];
    __shared__ unsigned char bp[TT][KK];

    for (int f = lane; f < TT * KK; f += 64) {
        int t = f / KK, kk = f - t * KK;
        em_s[f] = em_sum[((size_t)t * BB + b) * KK + kk];
    }
    __syncthreads();

    float trans_col[KK];
    float score = -1e30f;
    if (lane < KK) {
        #pragma unroll
        for (int i = 0; i < KK; i++) trans_col[i] = trans[i * KK + lane];
        score = start_trans[lane] + em_s[lane];
    }

    for (int t = 1; t < TT; t++) {
        float my = (lane < KK) ? score : -1e30f;
        float sarr[KK];
        #pragma unroll
        for (int i = 0; i < KK; i++) sarr[i] = __shfl(my, i);
        float best = -1e30f;
        int bi = 0;
        #pragma unroll
        for (int i = 0; i < KK; i++) {
            float cand = sarr[i] + trans_col[i];
            if (cand > best) { best = cand; bi = i; }
        }
        if (lane < KK) {
            bp[t][lane] = (unsigned char)bi;
            score = best + em_s[t * KK + lane];
        }
    }

    float fin = (lane < KK) ? (score + end_trans[lane]) : -1e30f;
    float farr[KK];
    #pragma unroll
    for (int jx = 0; jx < KK; jx++) farr[jx] = __shfl(fin, jx);
    float bestf = -1e30f;
    int bj = 0;
    #pragma unroll
    for (int jx = 0; jx < KK; jx++) {
        if (farr[jx] > bestf) { bestf = farr[jx]; bj = jx; }
    }

    if (lane == 0) {
        int tag = bj;
        out[b * TT + (TT - 1)] = tag;
        for (int t = TT - 1; t >= 1; t--) {
            tag = bp[t][tag];
            out[b * TT + t - 1] = tag;
        }
    }
}

// ---------------------------------------------------------------------------
extern "C" void kernel_launch(void* const* d_in, const int* in_sizes, int n_in,
                              void* d_out, int out_size, void* d_ws, size_t ws_size,
                              hipStream_t stream)
{
    const int*   x       = (const int*)  d_in[0];
    const float* emb     = (const float*)d_in[1];
    const float* w_ih_f  = (const float*)d_in[2];
    const float* w_hh_f  = (const float*)d_in[3];
    const float* b_ih_f  = (const float*)d_in[4];
    const float* b_hh_f  = (const float*)d_in[5];
    const float* w_ih_b  = (const float*)d_in[6];
    const float* w_hh_b  = (const float*)d_in[7];
    const float* b_ih_b  = (const float*)d_in[8];
    const float* b_hh_b  = (const float*)d_in[9];
    const float* W_tag   = (const float*)d_in[10];
    const float* b_tag   = (const float*)d_in[11];
    const float* start_t = (const float*)d_in[12];
    const float* end_t   = (const float*)d_in[13];
    const float* trans   = (const float*)d_in[14];
    int* out = (int*)d_out;

    // fixed-size pieces (floats)
    const size_t e_elems     = (size_t)TT * BB * 128;  // 33.5 MB
    const size_t hall_elems  = (size_t)TT * BB * 256;  // 67 MB
    const size_t em_elems    = (size_t)TT * BB * KK;   // 2.25 MB
    const size_t state_elems = (size_t)2 * 128 * 128;

    // pick chunk size C based on available workspace
    int C = 32;
    const int cands[5] = {512, 256, 128, 64, 32};
    for (int ci = 0; ci < 5; ci++) {
        size_t need = ((size_t)2 * cands[ci] * BB * 512
                       + e_elems + hall_elems + em_elems
                       + 2 * state_elems) * sizeof(float);
        if (ws_size >= need) { C = cands[ci]; break; }
    }

    float* buf_f   = (float*)d_ws;                       // C*128*512
    float* buf_b   = buf_f + (size_t)C * BB * 512;       // C*128*512
    float* em_sum  = buf_b + (size_t)C * BB * 512;       // T*B*9
    float* h_state = em_sum + em_elems;                  // 2*128*128
    float* c_state = h_state + state_elems;              // 2*128*128
    float* e       = c_state + state_elems;              // T*B*128
    float* h_all   = e + e_elems;                        // T*B*256

    gather_e<<<dim3((TT * BB) / 8), dim3(256), 0, stream>>>(x, emb, e);

    const int rounds = TT / C;
    for (int r = 0; r < rounds; r++) {
        const int t0f = r * C;
        const int t0b = TT - (r + 1) * C;
        dim3 gg(C, 4, 2);
        input_gemm<<<gg, dim3(256), 0, stream>>>(
            e, w_ih_f, w_ih_b, b_ih_f, b_hh_f, b_ih_b, b_hh_b,
            buf_f, buf_b, t0f, t0b);
        lstm_chunk<<<dim3(256), dim3(512), 0, stream>>>(
            buf_f, buf_b, w_hh_f, w_hh_b, h_all,
            h_state, c_state, t0f, t0b, C, (r == 0) ? 1 : 0);
    }
    emis_kernel<<<dim3((TT * BB) / 4), dim3(256), 0, stream>>>(
        h_all, W_tag, b_tag, em_sum);
    viterbi_kernel<<<dim3(BB), dim3(64), 0, stream>>>(
        em_sum, start_t, end_t, trans, out);
}